// Round 1
// baseline (2754.130 us; speedup 1.0000x reference)
//
#include <hip/hip_runtime.h>

#define B_   32
#define LQ_  96
#define NK_  2048
#define D_   384
#define H_   8
#define DH_  48
#define FF_  1536
#define NSELF_ 2144
#define MQ_  (B_*LQ_)   // 3072

typedef float  f32x4  __attribute__((ext_vector_type(4)));
typedef __bf16 bf16x8 __attribute__((ext_vector_type(8)));

__device__ __forceinline__ unsigned short f2bf(float f) {
  union { float f; unsigned u; } v; v.f = f;
  unsigned r = v.u + 0x7fffu + ((v.u >> 16) & 1u);
  return (unsigned short)(r >> 16);
}

// ---------------- time embedding: pe -> relu(@t_w1+b1) -> @t_w2+b2 -> silu ----
__global__ void time_embed_kernel(const float* __restrict__ ts,
                                  const float* __restrict__ w1, const float* __restrict__ b1,
                                  const float* __restrict__ w2, const float* __restrict__ b2,
                                  float* __restrict__ s_out) {
  int b = blockIdx.x, d = threadIdx.x;
  __shared__ float pe[384];
  __shared__ float h1[384];
  float t = ts[b];
  int dd = (d < 192) ? d : d - 192;
  float f = expf((float)dd * (-9.210340371976184f / 191.0f));
  float ang = t * f;
  pe[d] = (d < 192) ? sinf(ang) : cosf(ang);
  __syncthreads();
  float acc = b1[d];
  for (int k = 0; k < 384; ++k) acc += pe[k] * w1[k * 384 + d];
  h1[d] = fmaxf(acc, 0.f);
  __syncthreads();
  acc = b2[d];
  for (int k = 0; k < 384; ++k) acc += h1[k] * w2[k * 384 + d];
  s_out[b * 384 + d] = acc / (1.f + expf(-acc));   // silu
}

// ---------------- AdaLN modulation: mod[l][b] = silu(t)@ada_w[l] + ada_b[l] ---
__global__ void adaln_mod_kernel(const float* __restrict__ s,
                                 const float* __restrict__ aw, const float* __restrict__ ab,
                                 float* __restrict__ mod) {
  int b = blockIdx.x, l = blockIdx.y, c = threadIdx.x;
  __shared__ float ss[384];
  if (c < 384) ss[c] = s[b * 384 + c];
  __syncthreads();
  float acc = ab[l * 768 + c];
  const float* w = aw + (long)l * 384 * 768;
  for (int k = 0; k < 384; ++k) acc += ss[k] * w[k * 768 + c];
  mod[((long)l * 32 + b) * 768 + c] = acc;
}

// ---------------- RoPE pair tables: [B,N,192] cos/sin ------------------------
__global__ void rope_tab_kernel(const float* __restrict__ xyz,
                                float* __restrict__ ct, float* __restrict__ st,
                                int total, int N) {
  for (int i = blockIdx.x * blockDim.x + threadIdx.x; i < total;
       i += gridDim.x * blockDim.x) {
    int p = i % 192;
    int n = (i / 192) % N;
    int b = i / (192 * N);
    int a = p >> 6, j = p & 63;
    float div = expf((float)j * (-9.210340371976184f / 64.0f));
    float ang = xyz[((long)b * N + n) * 3 + a] * div;
    float sv, cv;
    sincosf(ang, &sv, &cv);
    ct[i] = cv; st[i] = sv;
  }
}

// ---------------- cast f32->bf16 with type_emb add at rows 2046/2047 ---------
__global__ void cast_type_kernel(const float* __restrict__ in, const float* __restrict__ temb,
                                 unsigned short* __restrict__ out, long total, int N) {
  for (long i = blockIdx.x * (long)blockDim.x + threadIdx.x; i < total;
       i += (long)gridDim.x * blockDim.x) {
    int d = (int)(i % 384);
    int n = (int)((i / 384) % N);
    float v = in[i];
    if (n == 2046) v += temb[3 * 384 + d];
    else if (n == 2047) v += temb[4 * 384 + d];
    out[i] = f2bf(v);
  }
}

// ---------------- weight transpose+cast: out[l][n][k] = bf16(in[l][k][n]) ----
__global__ void wtrans_kernel(const float* __restrict__ in, unsigned short* __restrict__ out,
                              long total, int K, int N) {
  for (long i = blockIdx.x * (long)blockDim.x + threadIdx.x; i < total;
       i += (long)gridDim.x * blockDim.x) {
    long l = i / ((long)K * N);
    long rem = i - l * (long)K * N;
    int n = (int)(rem / K);
    int k = (int)(rem % K);
    out[i] = f2bf(in[l * (long)K * N + (long)k * N + n]);
  }
}

// ---------------- AdaLN apply: xq = bf16(x*(1+scale)+shift) ------------------
__global__ void modx_kernel(const float* __restrict__ x, const float* __restrict__ modl,
                            unsigned short* __restrict__ xq) {
  int i = blockIdx.x * blockDim.x + threadIdx.x;
  if (i >= MQ_ * D_) return;
  int d = i % 384;
  int b = (i / 384) / 96;
  float sc = modl[b * 768 + d];
  float sh = modl[b * 768 + 384 + d];
  xq[i] = f2bf(x[i] * (1.f + sc) + sh);
}

// ---------------- MFMA GEMM: C[M,Nt] = A[M,K](bf16) x Bt[Nt,K]^T + bias ------
// 128x128 tile, BK=32, 4 waves, each wave 64x64 (4x4 of 16x16x32 MFMA).
#define EPI_BF16 0
#define EPI_RELU 1
#define EPI_F32  2
#define EPI_ROPE 3

template <int EPI>
__global__ __launch_bounds__(256)
void gemm_bt(const unsigned short* __restrict__ A, const unsigned short* __restrict__ Bt,
             const float* __restrict__ bias, void* __restrict__ Cout,
             int M, int Nt, int K,
             const float* __restrict__ cosA, const float* __restrict__ sinA, int strideA,
             const float* __restrict__ cosB, const float* __restrict__ sinB,
             int nPerRow, int split) {
  __shared__ __align__(16) unsigned short As[128 * 32];
  __shared__ __align__(16) unsigned short Bs[128 * 32];
  int tid = threadIdx.x, lane = tid & 63, wid = tid >> 6;
  int wm = (wid >> 1) * 64, wn = (wid & 1) * 64;
  long bm = (long)blockIdx.x * 128;
  int bn = blockIdx.y * 128;
  int r0 = tid >> 2, c0 = (tid & 3) * 8;
  const uint4* gA0 = (const uint4*)(A + (bm + r0) * K + c0);
  const uint4* gA1 = (const uint4*)(A + (bm + 64 + r0) * K + c0);
  const uint4* gB0 = (const uint4*)(Bt + (long)(bn + r0) * K + c0);
  const uint4* gB1 = (const uint4*)(Bt + (long)(bn + 64 + r0) * K + c0);
  f32x4 acc[4][4] = {};
  uint4 pa0 = gA0[0], pa1 = gA1[0], pb0 = gB0[0], pb1 = gB1[0];
  int nk = K >> 5;
  int la = lane & 15, lg = (lane >> 4) * 8;
  for (int kc = 0; kc < nk; ++kc) {
    *(uint4*)&As[r0 * 32 + c0] = pa0;
    *(uint4*)&As[(64 + r0) * 32 + c0] = pa1;
    *(uint4*)&Bs[r0 * 32 + c0] = pb0;
    *(uint4*)&Bs[(64 + r0) * 32 + c0] = pb1;
    __syncthreads();
    if (kc + 1 < nk) {
      int o = (kc + 1) * 4;
      pa0 = gA0[o]; pa1 = gA1[o]; pb0 = gB0[o]; pb1 = gB1[o];
    }
    bf16x8 af[4], bfr[4];
#pragma unroll
    for (int i = 0; i < 4; ++i) af[i] = *(const bf16x8*)&As[(wm + i * 16 + la) * 32 + lg];
#pragma unroll
    for (int j = 0; j < 4; ++j) bfr[j] = *(const bf16x8*)&Bs[(wn + j * 16 + la) * 32 + lg];
#pragma unroll
    for (int i = 0; i < 4; ++i)
#pragma unroll
      for (int j = 0; j < 4; ++j)
        acc[i][j] = __builtin_amdgcn_mfma_f32_16x16x32_bf16(af[i], bfr[j], acc[i][j], 0, 0, 0);
    __syncthreads();
  }
  int lr = (lane >> 4) * 4;
#pragma unroll
  for (int i = 0; i < 4; ++i) {
#pragma unroll
    for (int r = 0; r < 4; ++r) {
      long row = bm + wm + i * 16 + lr + r;
      const float* ct = nullptr; const float* st = nullptr; long ti = 0;
      if (EPI == EPI_ROPE) {
        int bb = (int)(row / nPerRow);
        int nn = (int)(row % nPerRow);
        if (nn < split) { ct = cosA; st = sinA; ti = ((long)bb * strideA + nn) * 192; }
        else            { ct = cosB; st = sinB; ti = ((long)bb * 96 + (nn - split)) * 192; }
      }
#pragma unroll
      for (int j = 0; j < 4; ++j) {
        int col = bn + wn + j * 16 + la;
        float v = acc[i][j][r] + bias[col];
        if (EPI == EPI_F32) {
          ((float*)Cout)[row * Nt + col] = v;
        } else if (EPI == EPI_BF16) {
          ((unsigned short*)Cout)[row * Nt + col] = f2bf(v);
        } else if (EPI == EPI_RELU) {
          ((unsigned short*)Cout)[row * Nt + col] = f2bf(fmaxf(v, 0.f));
        } else {
          float pv = __shfl_xor(v, 1);  // pair partner (col^1) lives in lane^1
          int p = ((col >> 7) << 6) + ((col & 127) >> 1);
          float cc = ct[ti + p], ss = st[ti + p];
          float o = (col & 1) ? (v * cc + pv * ss) : (v * cc - pv * ss);
          ((unsigned short*)Cout)[row * Nt + col] = f2bf(o);
        }
      }
    }
  }
}

// ---------------- flash attention: one block per (h,b), 6 waves x 16 q-rows --
__global__ __launch_bounds__(384)
void attn_kernel(const unsigned short* __restrict__ Q, const unsigned short* __restrict__ Kg,
                 const unsigned short* __restrict__ Vg, unsigned short* __restrict__ O,
                 int N) {
  int h = blockIdx.x, b = blockIdx.y;
  int tid = threadIdx.x, lane = tid & 63, w = tid >> 6;
  __shared__ __align__(16) unsigned short Qs[96][64];
  __shared__ __align__(16) unsigned short Ks[32][64];
  __shared__ __align__(16) unsigned short Vs[32][56];
  __shared__ __align__(16) unsigned short Ps[6][16][32];
  const uint4 z4 = {0u, 0u, 0u, 0u};
  for (int e = tid; e < 576; e += 384) {
    int row = e / 6, g = e % 6;
    *(uint4*)&Qs[row][g * 8] = *(const uint4*)&Q[((long)b * 96 + row) * 384 + h * 48 + g * 8];
  }
  for (int e = tid; e < 192; e += 384) {
    int row = e / 2, g = e % 2;
    *(uint4*)&Qs[row][48 + g * 8] = z4;
  }
  if (tid < 64) {
    int row = tid >> 1, g = tid & 1;
    *(uint4*)&Ks[row][48 + g * 8] = z4;   // K dim pad 48..63, constant
  }
  __syncthreads();
  int la = lane & 15, lg = (lane >> 4) * 8;
  bf16x8 qf0 = *(const bf16x8*)&Qs[w * 16 + la][lg];
  bf16x8 qf1 = *(const bf16x8*)&Qs[w * 16 + la][32 + lg];
  float m[4], lsum[4];
  f32x4 of[3] = {};
#pragma unroll
  for (int r = 0; r < 4; ++r) { m[r] = -1e30f; lsum[r] = 0.f; }
  int stt = (tid < 192) ? tid : tid - 192;
  int srow = stt / 6, sg = (stt % 6) * 8;
  const unsigned short* gbase = (tid < 192) ? Kg : Vg;
  const uint4* gsrc = (const uint4*)(gbase + ((long)b * N + srow) * 384 + h * 48 + sg);
  uint4 pref = gsrc[0];
  int nit = N / 32;
  const float SCALE = 0.14433756729740643f;  // 1/sqrt(48)
  for (int it = 0; it < nit; ++it) {
    if (tid < 192) *(uint4*)&Ks[srow][sg] = pref;
    else           *(uint4*)&Vs[srow][sg] = pref;
    __syncthreads();
    if (it + 1 < nit) pref = gsrc[(it + 1) * 1536];  // +32 rows * 384 elem = 1536 uint4
    f32x4 sc[2] = {};
#pragma unroll
    for (int ctile = 0; ctile < 2; ++ctile) {
      bf16x8 kf0 = *(const bf16x8*)&Ks[ctile * 16 + la][lg];
      bf16x8 kf1 = *(const bf16x8*)&Ks[ctile * 16 + la][32 + lg];
      sc[ctile] = __builtin_amdgcn_mfma_f32_16x16x32_bf16(qf0, kf0, sc[ctile], 0, 0, 0);
      sc[ctile] = __builtin_amdgcn_mfma_f32_16x16x32_bf16(qf1, kf1, sc[ctile], 0, 0, 0);
    }
    float mx[4], rs[4], al[4];
#pragma unroll
    for (int r = 0; r < 4; ++r) {
      sc[0][r] *= SCALE; sc[1][r] *= SCALE;
      mx[r] = fmaxf(sc[0][r], sc[1][r]);
    }
#pragma unroll
    for (int d = 1; d < 16; d <<= 1)
#pragma unroll
      for (int r = 0; r < 4; ++r) mx[r] = fmaxf(mx[r], __shfl_xor(mx[r], d));
#pragma unroll
    for (int r = 0; r < 4; ++r) {
      float mn = fmaxf(m[r], mx[r]);
      al[r] = __expf(m[r] - mn);
      sc[0][r] = __expf(sc[0][r] - mn);
      sc[1][r] = __expf(sc[1][r] - mn);
      rs[r] = sc[0][r] + sc[1][r];
      m[r] = mn;
    }
#pragma unroll
    for (int d = 1; d < 16; d <<= 1)
#pragma unroll
      for (int r = 0; r < 4; ++r) rs[r] += __shfl_xor(rs[r], d);
#pragma unroll
    for (int r = 0; r < 4; ++r) lsum[r] = lsum[r] * al[r] + rs[r];
#pragma unroll
    for (int dt = 0; dt < 3; ++dt)
#pragma unroll
      for (int r = 0; r < 4; ++r) of[dt][r] *= al[r];
    int prow = (lane >> 4) * 4;
#pragma unroll
    for (int ctile = 0; ctile < 2; ++ctile)
#pragma unroll
      for (int r = 0; r < 4; ++r)
        Ps[w][prow + r][ctile * 16 + la] = f2bf(sc[ctile][r]);
    __asm__ volatile("s_waitcnt lgkmcnt(0)" ::: "memory");  // wave-local C->A relayout
    bf16x8 pf = *(const bf16x8*)&Ps[w][la][lg];
#pragma unroll
    for (int dt = 0; dt < 3; ++dt) {
      union { bf16x8 v; unsigned short u[8]; } vf;
#pragma unroll
      for (int j = 0; j < 8; ++j) vf.u[j] = Vs[lg + j][dt * 16 + la];
      of[dt] = __builtin_amdgcn_mfma_f32_16x16x32_bf16(pf, vf.v, of[dt], 0, 0, 0);
    }
    __syncthreads();
  }
#pragma unroll
  for (int dt = 0; dt < 3; ++dt)
#pragma unroll
    for (int r = 0; r < 4; ++r) {
      int qrow = w * 16 + (lane >> 4) * 4 + r;
      float v = of[dt][r] / lsum[r];
      O[((long)b * 96 + qrow) * 384 + h * 48 + dt * 16 + la] = f2bf(v);
    }
}

// ---------------- residual + LayerNorm, emits f32 + bf16 ---------------------
__global__ __launch_bounds__(128)
void ln_res_kernel(const float* __restrict__ xin, const float* __restrict__ delta,
                   const float* __restrict__ g, const float* __restrict__ bt,
                   float* __restrict__ xout, unsigned short* __restrict__ xbf) {
  int row = blockIdx.x, tid = threadIdx.x;
  __shared__ float red[128];
  float v[3];
#pragma unroll
  for (int i = 0; i < 3; ++i) {
    int d = tid + i * 128;
    v[i] = xin[(long)row * 384 + d] + delta[(long)row * 384 + d];
  }
  red[tid] = v[0] + v[1] + v[2];
  __syncthreads();
  for (int t = 64; t > 0; t >>= 1) { if (tid < t) red[tid] += red[tid + t]; __syncthreads(); }
  float mean = red[0] / 384.f;
  __syncthreads();
  float q = 0.f;
#pragma unroll
  for (int i = 0; i < 3; ++i) { float d0 = v[i] - mean; q += d0 * d0; }
  red[tid] = q;
  __syncthreads();
  for (int t = 64; t > 0; t >>= 1) { if (tid < t) red[tid] += red[tid + t]; __syncthreads(); }
  float rstd = rsqrtf(red[0] / 384.f + 1e-5f);
#pragma unroll
  for (int i = 0; i < 3; ++i) {
    int d = tid + i * 128;
    float o = (v[i] - mean) * rstd * g[d] + bt[d];
    xout[(long)row * 384 + d] = o;
    xbf[(long)row * 384 + d] = f2bf(o);
  }
}

// ---------------- fp32 row GEMM for the MLP heads ----------------------------
__global__ void rowgemm_kernel(const float* __restrict__ A, const float* __restrict__ W,
                               const float* __restrict__ bias, float* __restrict__ out,
                               int K, int Nc, int ldo, int ooff,
                               int grp, int gstride, int roff, int relu) {
  int r = blockIdx.x, tid = threadIdx.x;
  long arow = (grp > 0) ? ((long)(r / grp) * gstride + roff + (r % grp)) : r;
  __shared__ float as[1536];
  for (int k = tid; k < K; k += blockDim.x) as[k] = A[arow * K + k];
  __syncthreads();
  if (tid < Nc) {
    float acc = bias[tid];
    for (int k = 0; k < K; ++k) acc += as[k] * W[(long)k * Nc + tid];
    if (relu) acc = fmaxf(acc, 0.f);
    out[(long)r * ldo + ooff + tid] = acc;
  }
}

// =============================================================================
extern "C" void kernel_launch(void* const* d_in, const int* in_sizes, int n_in,
                              void* d_out, int out_size, void* d_ws, size_t ws_size,
                              hipStream_t stream) {
  const float* q_in    = (const float*)d_in[0];
  const float* k_cross = (const float*)d_in[1];
  const float* k_self  = (const float*)d_in[2];
  const float* q_xyz   = (const float*)d_in[3];
  const float* k_xyz   = (const float*)d_in[4];
  const float* tsteps  = (const float*)d_in[5];
  const float* t_w1 = (const float*)d_in[6];
  const float* t_b1 = (const float*)d_in[7];
  const float* t_w2 = (const float*)d_in[8];
  const float* t_b2 = (const float*)d_in[9];
  const float* type_emb = (const float*)d_in[10];
  const float* ada_w = (const float*)d_in[11];
  const float* ada_b = (const float*)d_in[12];
  const float* wq = (const float*)d_in[13]; const float* bq = (const float*)d_in[14];
  const float* wk = (const float*)d_in[15]; const float* bk = (const float*)d_in[16];
  const float* wv = (const float*)d_in[17]; const float* bv = (const float*)d_in[18];
  const float* wo = (const float*)d_in[19]; const float* bo = (const float*)d_in[20];
  const float* ln1g = (const float*)d_in[21]; const float* ln1b = (const float*)d_in[22];
  const float* fw1 = (const float*)d_in[23]; const float* fb1 = (const float*)d_in[24];
  const float* fw2 = (const float*)d_in[25]; const float* fb2 = (const float*)d_in[26];
  const float* ln2g = (const float*)d_in[27]; const float* ln2b = (const float*)d_in[28];
  const float* hw[9]; const float* hb[9];
  for (int i = 0; i < 9; ++i) { hw[i] = (const float*)d_in[29 + 2 * i]; hb[i] = (const float*)d_in[30 + 2 * i]; }

  char* ws = (char*)d_ws;
  size_t off = 0;
  auto alloc = [&](size_t bytes) -> void* {
    void* p = ws + off;
    off += (bytes + 255) & ~(size_t)255;
    return p;
  };
  float* s_silu = (float*)alloc((size_t)32 * 384 * 4);
  float* mod    = (float*)alloc((size_t)6 * 32 * 768 * 4);
  float* qcos   = (float*)alloc((size_t)32 * 96 * 192 * 4);
  float* qsin   = (float*)alloc((size_t)32 * 96 * 192 * 4);
  float* kcos   = (float*)alloc((size_t)32 * 2048 * 192 * 4);
  float* ksin   = (float*)alloc((size_t)32 * 2048 * 192 * 4);
  unsigned short* kcb  = (unsigned short*)alloc((size_t)32 * 2048 * 384 * 2);
  unsigned short* ksb  = (unsigned short*)alloc((size_t)32 * 2144 * 384 * 2);
  unsigned short* wqt  = (unsigned short*)alloc((size_t)6 * 384 * 384 * 2);
  unsigned short* wkt  = (unsigned short*)alloc((size_t)6 * 384 * 384 * 2);
  unsigned short* wvt  = (unsigned short*)alloc((size_t)6 * 384 * 384 * 2);
  unsigned short* wot  = (unsigned short*)alloc((size_t)6 * 384 * 384 * 2);
  unsigned short* fw1t = (unsigned short*)alloc((size_t)6 * 384 * 1536 * 2);
  unsigned short* fw2t = (unsigned short*)alloc((size_t)6 * 384 * 1536 * 2);
  float* x            = (float*)alloc((size_t)MQ_ * 384 * 4);
  unsigned short* xbf  = (unsigned short*)alloc((size_t)MQ_ * 384 * 2);
  unsigned short* xqb  = (unsigned short*)alloc((size_t)MQ_ * 384 * 2);
  unsigned short* qrope= (unsigned short*)alloc((size_t)MQ_ * 384 * 2);
  unsigned short* Kc   = (unsigned short*)alloc((size_t)32 * 2144 * 384 * 2);
  unsigned short* Vc   = (unsigned short*)alloc((size_t)32 * 2144 * 384 * 2);
  unsigned short* aout = (unsigned short*)alloc((size_t)MQ_ * 384 * 2);
  float* tmp          = (float*)alloc((size_t)MQ_ * 384 * 4);
  unsigned short* ffh  = (unsigned short*)alloc((size_t)MQ_ * 1536 * 2);
  float* h1b          = (float*)alloc((size_t)1024 * 384 * 4);
  float* h2b          = (float*)alloc((size_t)1024 * 384 * 4);
  (void)ws_size; (void)in_sizes; (void)n_in; (void)out_size;

  // ---- prep (layer-invariant) ----
  time_embed_kernel<<<32, 384, 0, stream>>>(tsteps, t_w1, t_b1, t_w2, t_b2, s_silu);
  adaln_mod_kernel<<<dim3(32, 6), 768, 0, stream>>>(s_silu, ada_w, ada_b, mod);
  rope_tab_kernel<<<2048, 256, 0, stream>>>(q_xyz, qcos, qsin, 32 * 96 * 192, 96);
  rope_tab_kernel<<<4096, 256, 0, stream>>>(k_xyz, kcos, ksin, 32 * 2048 * 192, 2048);
  cast_type_kernel<<<4096, 256, 0, stream>>>(k_cross, type_emb, kcb, (long)32 * 2048 * 384, 2048);
  cast_type_kernel<<<4096, 256, 0, stream>>>(k_self, type_emb, ksb, (long)32 * 2144 * 384, 2144);
  wtrans_kernel<<<1024, 256, 0, stream>>>(wq, wqt, (long)6 * 384 * 384, 384, 384);
  wtrans_kernel<<<1024, 256, 0, stream>>>(wk, wkt, (long)6 * 384 * 384, 384, 384);
  wtrans_kernel<<<1024, 256, 0, stream>>>(wv, wvt, (long)6 * 384 * 384, 384, 384);
  wtrans_kernel<<<1024, 256, 0, stream>>>(wo, wot, (long)6 * 384 * 384, 384, 384);
  wtrans_kernel<<<2048, 256, 0, stream>>>(fw1, fw1t, (long)6 * 384 * 1536, 384, 1536);
  wtrans_kernel<<<2048, 256, 0, stream>>>(fw2, fw2t, (long)6 * 1536 * 384, 1536, 384);
  hipMemcpyAsync(x, q_in, (size_t)MQ_ * 384 * 4, hipMemcpyDeviceToDevice, stream);

  // ---- 6 transformer layers ----
  for (int l = 0; l < 6; ++l) {
    int Nl = (l < 2) ? 2048 : 2144;
    const unsigned short* kvsrc = (l < 2) ? kcb : ksb;
    modx_kernel<<<(MQ_ * 384 + 255) / 256, 256, 0, stream>>>(x, mod + (long)l * 32 * 768, xqb);
    gemm_bt<EPI_ROPE><<<dim3(24, 3), 256, 0, stream>>>(
        xqb, wqt + (long)l * 384 * 384, bq + l * 384, qrope, MQ_, 384, 384,
        qcos, qsin, 96, qcos, qsin, 96, 96);
    gemm_bt<EPI_ROPE><<<dim3(32 * Nl / 128, 3), 256, 0, stream>>>(
        kvsrc, wkt + (long)l * 384 * 384, bk + l * 384, Kc, 32 * Nl, 384, 384,
        kcos, ksin, 2048, qcos, qsin, Nl, 2048);
    gemm_bt<EPI_BF16><<<dim3(32 * Nl / 128, 3), 256, 0, stream>>>(
        kvsrc, wvt + (long)l * 384 * 384, bv + l * 384, Vc, 32 * Nl, 384, 384,
        nullptr, nullptr, 1, nullptr, nullptr, Nl, 0);
    attn_kernel<<<dim3(8, 32), 384, 0, stream>>>(qrope, Kc, Vc, aout, Nl);
    gemm_bt<EPI_F32><<<dim3(24, 3), 256, 0, stream>>>(
        aout, wot + (long)l * 384 * 384, bo + l * 384, tmp, MQ_, 384, 384,
        nullptr, nullptr, 1, nullptr, nullptr, 96, 0);
    ln_res_kernel<<<MQ_, 128, 0, stream>>>(x, tmp, ln1g + l * 384, ln1b + l * 384, x, xbf);
    gemm_bt<EPI_RELU><<<dim3(24, 12), 256, 0, stream>>>(
        xbf, fw1t + (long)l * 1536 * 384, fb1 + l * 1536, ffh, MQ_, 1536, 384,
        nullptr, nullptr, 1, nullptr, nullptr, 96, 0);
    gemm_bt<EPI_F32><<<dim3(24, 3), 256, 0, stream>>>(
        ffh, fw2t + (long)l * 384 * 1536, fb2 + l * 384, tmp, MQ_, 384, 1536,
        nullptr, nullptr, 1, nullptr, nullptr, 96, 0);
    ln_res_kernel<<<MQ_, 128, 0, stream>>>(x, tmp, ln2g + l * 384, ln2b + l * 384, x, xbf);
  }

  // ---- MLP heads (fp32) ----
  const int ooffs[3] = {0, 31, 62};
  const int nouts[3] = {31, 31, 9};
  for (int hd = 0; hd < 3; ++hd) {
    rowgemm_kernel<<<1024, 384, 0, stream>>>(x, hw[hd * 3 + 0], hb[hd * 3 + 0], h1b,
                                             384, 384, 384, 0, 32, 96, hd * 32, 1);
    rowgemm_kernel<<<1024, 384, 0, stream>>>(h1b, hw[hd * 3 + 1], hb[hd * 3 + 1], h2b,
                                             384, 384, 384, 0, 0, 0, 0, 1);
    rowgemm_kernel<<<1024, 64, 0, stream>>>(h2b, hw[hd * 3 + 2], hb[hd * 3 + 2], (float*)d_out,
                                            384, nouts[hd], 71, ooffs[hd], 0, 0, 0, 0);
  }
}